// Round 3
// baseline (623.984 us; speedup 1.0000x reference)
//
#include <hip/hip_runtime.h>
#include <hip/hip_bf16.h>
#include <cstdint>

#define NANCH 17064
#define KTOP  1000
#define NCLS  80

typedef unsigned long long u64;
typedef unsigned int u32;

__device__ __forceinline__ float sigmoidf_(float x) {
  return 1.0f / (1.0f + expf(-x));
}

// ---------------------------------------------------------------------------
// Kernel 1: per-anchor score / class / box decode.
// Level shapes (100,128)(50,64)(25,32)(13,16)(7,8): widths are powers of two
// so y/x come from shifts. Consecutive threads share a level and read
// consecutive x -> coalesced per class iteration.
// ---------------------------------------------------------------------------
__global__ void __launch_bounds__(256) fcos_score_kernel(
    const float* __restrict__ cls0, const float* __restrict__ cnt0, const float* __restrict__ reg0,
    const float* __restrict__ cls1, const float* __restrict__ cnt1, const float* __restrict__ reg1,
    const float* __restrict__ cls2, const float* __restrict__ cnt2, const float* __restrict__ reg2,
    const float* __restrict__ cls3, const float* __restrict__ cnt3, const float* __restrict__ reg3,
    const float* __restrict__ cls4, const float* __restrict__ cnt4, const float* __restrict__ reg4,
    u64* __restrict__ keys, int* __restrict__ classes, float4* __restrict__ boxes)
{
  int a = blockIdx.x * blockDim.x + threadIdx.x;
  int b = blockIdx.y;
  if (a >= NANCH) return;

  const float *clsP, *cntP, *regP;
  int hw, wlog, stride, half, local;
  if (a < 12800)      { clsP=cls0; cntP=cnt0; regP=reg0; hw=12800; wlog=7; stride=8;   half=4;  local=a; }
  else if (a < 16000) { clsP=cls1; cntP=cnt1; regP=reg1; hw=3200;  wlog=6; stride=16;  half=8;  local=a-12800; }
  else if (a < 16800) { clsP=cls2; cntP=cnt2; regP=reg2; hw=800;   wlog=5; stride=32;  half=16; local=a-16000; }
  else if (a < 17008) { clsP=cls3; cntP=cnt3; regP=reg3; hw=208;   wlog=4; stride=64;  half=32; local=a-16800; }
  else                { clsP=cls4; cntP=cnt4; regP=reg4; hw=56;    wlog=3; stride=128; half=64; local=a-17008; }

  int y = local >> wlog;
  int x = local & ((1 << wlog) - 1);

  // max/argmax over sigmoid values (strict '>' == jnp.argmax first-max tie-break)
  const float* cp = clsP + (long)b * NCLS * hw + local;
  float best = -1.0f; int bestc = 0;
  #pragma unroll 4
  for (int c = 0; c < NCLS; ++c) {
    float v = cp[(long)c * hw];
    float s = sigmoidf_(v);
    if (s > best) { best = s; bestc = c; }
  }

  float cs = sigmoidf_(cntP[(long)b * hw + local]);
  float score = __fsqrt_rn(__fmul_rn(best, cs));

  const float* rp = regP + (long)b * 4 * hw + local;
  float r0 = rp[0], r1 = rp[hw], r2 = rp[2*hw], r3 = rp[3*hw];
  float cx = (float)(x * stride + half);
  float cy = (float)(y * stride + half);

  long gi = (long)b * NANCH + a;
  // unique sortable key: descending score, ties -> smaller anchor index first
  keys[gi]    = ((u64)__float_as_uint(score) << 32) | (u32)(~(u32)a);
  classes[gi] = bestc + 1;
  boxes[gi]   = make_float4(cx - r0, cy - r1, cx + r2, cy + r3);
}

// ---------------------------------------------------------------------------
// Kernel 2 (one block per batch, 1024 threads):
//   A) radix-select exact 1000th-largest 64-bit key (8x 8-bit digit passes)
//   B) compact the exactly-1000 selected keys, bitonic sort in LDS
//   C) gather class/box, block-reduce max_coord, build offset boxes in LDS
//   D) NMS: build 256-row chunks of the 1000x1024-bit suppression matrix in
//      LDS, wave 0 runs the serial greedy scan (16 lanes hold removed mask)
//   E) write the four outputs
// ---------------------------------------------------------------------------
struct ShmA { u64 skeys[1024]; u32 hist[256]; };
struct ShmB {
  float ox1[1024], oy1[1024], ox2[1024], oy2[1024], oarea[1024]; // 20 KB
  u64   chunk[256 * 16];                                          // 32 KB
  int   valid[1024];                                              // 4 KB
  int   keep[1024];                                               // 4 KB
};

__global__ void __launch_bounds__(1024) fcos_topk_nms_kernel(
    const u64* __restrict__ keys, const int* __restrict__ classes,
    const float4* __restrict__ boxes, float* __restrict__ out)
{
  __shared__ union { ShmA a; ShmB b; } sh;   // ~60 KB
  __shared__ u64 s_prefix;
  __shared__ u32 s_krem, s_cnt;
  __shared__ float s_red[16];
  __shared__ float s_maxc;

  const int tid = threadIdx.x;
  const int b   = blockIdx.x;
  const int lane = tid & 63;
  const u64* bkeys = keys + (long)b * NANCH;

  if (tid == 0) { s_prefix = 0; s_krem = KTOP; s_cnt = 0; }

  // ---- A: radix select the 1000th-largest key -----------------------------
  for (int d = 56; d >= 0; d -= 8) {
    if (tid < 256) sh.a.hist[tid] = 0;
    __syncthreads();
    u64 pfx = s_prefix;
    for (int i = tid; i < NANCH; i += 1024) {
      u64 k = bkeys[i];
      bool ok = (d == 56) || ((k >> (d + 8)) == pfx);   // || short-circuits: no shift-by-64
      if (ok) atomicAdd(&sh.a.hist[(u32)((k >> d) & 255)], 1u);
    }
    __syncthreads();
    if (tid == 0) {
      u32 cum = 0, kr = s_krem;
      for (int bin = 255; bin >= 0; --bin) {
        u32 h = sh.a.hist[bin];
        if (cum + h >= kr) { s_prefix = (s_prefix << 8) | (u32)bin; s_krem = kr - cum; break; }
        cum += h;
      }
    }
    __syncthreads();
  }
  const u64 T = s_prefix;   // exact 1000th-largest key (keys are unique)

  // ---- B: compact + bitonic sort (store inverted keys, sort ascending) ----
  sh.a.skeys[tid] = ~0ULL;  // pad = smallest real key -> sorts to the end
  __syncthreads();
  for (int i = tid; i < NANCH; i += 1024) {
    u64 k = bkeys[i];
    if (k >= T) { u32 p = atomicAdd(&s_cnt, 1u); if (p < 1024) sh.a.skeys[p] = ~k; }
  }
  __syncthreads();

  for (u32 sz = 2; sz <= 1024; sz <<= 1) {
    for (u32 st = sz >> 1; st > 0; st >>= 1) {
      __syncthreads();
      u32 i = tid, j = i ^ st;
      if (j > i) {
        u64 A = sh.a.skeys[i], B = sh.a.skeys[j];
        bool up = ((i & sz) == 0);
        if ((A > B) == up) { sh.a.skeys[i] = B; sh.a.skeys[j] = A; }
      }
    }
  }
  __syncthreads();

  // ---- C: extract rank tid, gather, max_coord, offset boxes ---------------
  u64 key = ~sh.a.skeys[tid];
  float score = __uint_as_float((u32)(key >> 32));
  int   idx   = (int)(~(u32)(key & 0xFFFFFFFFu));
  float4 box  = make_float4(0.f, 0.f, 0.f, 0.f);
  int    cls  = 0;
  if (tid < KTOP) {
    long gi = (long)b * NANCH + idx;
    cls = classes[gi];
    box = boxes[gi];
  } else {
    score = 0.0f;
  }
  int valid = (tid < KTOP) && (score >= 0.05f);

  float m = valid ? fmaxf(fmaxf(box.x, box.y), fmaxf(box.z, box.w)) : 0.0f;
  #pragma unroll
  for (int o = 32; o > 0; o >>= 1) m = fmaxf(m, __shfl_xor(m, o, 64));
  if (lane == 0) s_red[tid >> 6] = m;
  __syncthreads();               // also: everyone is done reading sh.a
  if (tid == 0) {
    float mm = 0.0f;
    #pragma unroll
    for (int i2 = 0; i2 < 16; ++i2) mm = fmaxf(mm, s_red[i2]);
    s_maxc = mm;                 // max_coord (>= 0 by identity)
  }
  __syncthreads();

  float off = __fmul_rn((float)cls, __fadd_rn(s_maxc, 1.0f));
  float X1 = box.x + off, Y1 = box.y + off, X2 = box.z + off, Y2 = box.w + off;
  sh.b.ox1[tid] = X1; sh.b.oy1[tid] = Y1; sh.b.ox2[tid] = X2; sh.b.oy2[tid] = Y2;
  sh.b.oarea[tid] = __fmul_rn(__fadd_rn(__fsub_rn(X2, X1), 1.0f),
                              __fadd_rn(__fsub_rn(Y2, Y1), 1.0f));
  sh.b.valid[tid] = valid;
  sh.b.keep[tid]  = 0;
  __syncthreads();

  // ---- D: chunked suppression-matrix build + serial greedy scan -----------
  u64 removed = 0;   // lanes 0..15 of wave 0 hold the 1024-bit removed mask
  for (int ch = 0; ch < 4; ++ch) {
    const int rowbase = ch * 256;
    #pragma unroll
    for (int it = 0; it < 4; ++it) {
      int w  = it * 1024 + tid;
      int rc = w >> 4;           // row within chunk 0..255
      int wc = w & 15;           // 64-bit word column 0..15
      int r  = rowbase + rc;
      u64 bits = 0;
      if (r < KTOP) {
        float rx1 = sh.b.ox1[r], ry1 = sh.b.oy1[r];
        float rx2 = sh.b.ox2[r], ry2 = sh.b.oy2[r];
        float ra  = sh.b.oarea[r];
        for (int kk = 0; kk < 64; ++kk) {
          int k2 = (kk + lane) & 63;          // lane swizzle: kill bank conflicts
          int j  = wc * 64 + k2;
          if (j < KTOP) {
            float xmn = fmaxf(rx1, sh.b.ox1[j]);
            float ymn = fmaxf(ry1, sh.b.oy1[j]);
            float xmx = fminf(rx2, sh.b.ox2[j]);
            float ymx = fminf(ry2, sh.b.oy2[j]);
            float dx   = fmaxf(__fsub_rn(xmx, xmn), 0.0f);
            float dy   = fmaxf(__fsub_rn(ymx, ymn), 0.0f);
            float inter= __fmul_rn(dx, dy);
            float den  = __fsub_rn(__fadd_rn(ra, sh.b.oarea[j]), inter);
            float iou  = __fdiv_rn(inter, den);
            if (iou > 0.6f) bits |= (1ULL << k2);
          }
        }
      }
      sh.b.chunk[rc * 16 + wc] = bits;
    }
    __syncthreads();
    if (tid < 64) {
      for (int rr = 0; rr < 256; ++rr) {
        int i = rowbase + rr;
        if (i >= KTOP) break;
        u64 rw  = __shfl(removed, i >> 6, 64);
        bool sup = (rw >> (i & 63)) & 1ULL;
        bool kp  = sh.b.valid[i] && !sup;
        u64 roww = sh.b.chunk[rr * 16 + (lane & 15)];
        if (tid == 0) sh.b.keep[i] = kp;
        if (kp && lane < 16) removed |= roww;
      }
    }
    __syncthreads();
  }

  // ---- E: outputs: scores | classes | boxes | keep (all as f32) -----------
  if (tid < KTOP) {
    int kp = sh.b.keep[tid];
    float kf = kp ? 1.0f : 0.0f;
    int gi = b * KTOP + tid;
    out[gi]          = score * kf;
    out[16000 + gi]  = kp ? (float)cls : 0.0f;
    float4 ob = make_float4(box.x * kf, box.y * kf, box.z * kf, box.w * kf);
    *reinterpret_cast<float4*>(out + 32000 + (long)gi * 4) = ob;
    out[96000 + gi]  = kf;
  }
}

// ---------------------------------------------------------------------------
extern "C" void kernel_launch(void* const* d_in, const int* in_sizes, int n_in,
                              void* d_out, int out_size, void* d_ws, size_t ws_size,
                              hipStream_t stream) {
  const float *cls[5], *cnt[5], *reg[5];
  for (int i = 0; i < 5; ++i) {
    cls[i] = (const float*)d_in[3*i + 0];
    cnt[i] = (const float*)d_in[3*i + 1];
    reg[i] = (const float*)d_in[3*i + 2];
  }
  char* ws = (char*)d_ws;
  u64*    keys    = (u64*)ws;                  // 16*17064*8  = 2,184,192 B
  int*    classes = (int*)(ws + 2184192);      // 16*17064*4  = 1,092,096 B
  float4* boxes   = (float4*)(ws + 3276288);   // 16*17064*16 = 4,368,384 B (16B aligned)
  float*  out     = (float*)d_out;             // 112000 floats

  dim3 g1((NANCH + 255) / 256, 16);
  fcos_score_kernel<<<g1, 256, 0, stream>>>(
      cls[0], cnt[0], reg[0], cls[1], cnt[1], reg[1], cls[2], cnt[2], reg[2],
      cls[3], cnt[3], reg[3], cls[4], cnt[4], reg[4], keys, classes, boxes);

  fcos_topk_nms_kernel<<<16, 1024, 0, stream>>>(keys, classes, boxes, out);
}

// Round 4
// 391.097 us; speedup vs baseline: 1.5955x; 1.5955x over previous
//
#include <hip/hip_runtime.h>
#include <hip/hip_bf16.h>
#include <cstdint>

#define NANCH 17064
#define KTOP  1000
#define NCLS  80

typedef unsigned long long u64;
typedef unsigned int u32;

__device__ __forceinline__ float sigmoidf_(float x) {
  return 1.0f / (1.0f + expf(-x));
}

// ---------------------------------------------------------------------------
// K1: per-anchor score / class / box decode.  (UNCHANGED from passing version)
// ---------------------------------------------------------------------------
__global__ void __launch_bounds__(256) fcos_score_kernel(
    const float* __restrict__ cls0, const float* __restrict__ cnt0, const float* __restrict__ reg0,
    const float* __restrict__ cls1, const float* __restrict__ cnt1, const float* __restrict__ reg1,
    const float* __restrict__ cls2, const float* __restrict__ cnt2, const float* __restrict__ reg2,
    const float* __restrict__ cls3, const float* __restrict__ cnt3, const float* __restrict__ reg3,
    const float* __restrict__ cls4, const float* __restrict__ cnt4, const float* __restrict__ reg4,
    u64* __restrict__ keys, int* __restrict__ classes, float4* __restrict__ boxes)
{
  int a = blockIdx.x * blockDim.x + threadIdx.x;
  int b = blockIdx.y;
  if (a >= NANCH) return;

  const float *clsP, *cntP, *regP;
  int hw, wlog, stride, half, local;
  if (a < 12800)      { clsP=cls0; cntP=cnt0; regP=reg0; hw=12800; wlog=7; stride=8;   half=4;  local=a; }
  else if (a < 16000) { clsP=cls1; cntP=cnt1; regP=reg1; hw=3200;  wlog=6; stride=16;  half=8;  local=a-12800; }
  else if (a < 16800) { clsP=cls2; cntP=cnt2; regP=reg2; hw=800;   wlog=5; stride=32;  half=16; local=a-16000; }
  else if (a < 17008) { clsP=cls3; cntP=cnt3; regP=reg3; hw=208;   wlog=4; stride=64;  half=32; local=a-16800; }
  else                { clsP=cls4; cntP=cnt4; regP=reg4; hw=56;    wlog=3; stride=128; half=64; local=a-17008; }

  int y = local >> wlog;
  int x = local & ((1 << wlog) - 1);

  const float* cp = clsP + (long)b * NCLS * hw + local;
  float best = -1.0f; int bestc = 0;
  #pragma unroll 4
  for (int c = 0; c < NCLS; ++c) {
    float v = cp[(long)c * hw];
    float s = sigmoidf_(v);
    if (s > best) { best = s; bestc = c; }
  }

  float cs = sigmoidf_(cntP[(long)b * hw + local]);
  float score = __fsqrt_rn(__fmul_rn(best, cs));

  const float* rp = regP + (long)b * 4 * hw + local;
  float r0 = rp[0], r1 = rp[hw], r2 = rp[2*hw], r3 = rp[3*hw];
  float cx = (float)(x * stride + half);
  float cy = (float)(y * stride + half);

  long gi = (long)b * NANCH + a;
  keys[gi]    = ((u64)__float_as_uint(score) << 32) | (u32)(~(u32)a);
  classes[gi] = bestc + 1;
  boxes[gi]   = make_float4(cx - r0, cy - r1, cx + r2, cy + r3);
}

// ---------------------------------------------------------------------------
// K2: per-batch top-1000 (radix select + bitonic sort), gather, offset boxes.
// Same math as the passing version; results now go to ws instead of LDS.
// ---------------------------------------------------------------------------
struct ShmA { u64 skeys[1024]; u32 hist[256]; };

__global__ void __launch_bounds__(1024) fcos_topk_kernel(
    const u64* __restrict__ keys, const int* __restrict__ classes,
    const float4* __restrict__ boxes,
    float* __restrict__ t_score, int* __restrict__ t_cls, float4* __restrict__ t_box,
    float* __restrict__ ox1, float* __restrict__ oy1,
    float* __restrict__ ox2, float* __restrict__ oy2,
    float* __restrict__ oarea, u64* __restrict__ validbits)
{
  __shared__ ShmA sh;
  __shared__ u64 s_prefix;
  __shared__ u32 s_krem, s_cnt;
  __shared__ float s_red[16];
  __shared__ float s_maxc;

  const int tid = threadIdx.x;
  const int b   = blockIdx.x;
  const int lane = tid & 63;
  const u64* bkeys = keys + (long)b * NANCH;

  if (tid == 0) { s_prefix = 0; s_krem = KTOP; s_cnt = 0; }

  // ---- A: radix select the 1000th-largest key -----------------------------
  for (int d = 56; d >= 0; d -= 8) {
    if (tid < 256) sh.hist[tid] = 0;
    __syncthreads();
    u64 pfx = s_prefix;
    for (int i = tid; i < NANCH; i += 1024) {
      u64 k = bkeys[i];
      bool ok = (d == 56) || ((k >> (d + 8)) == pfx);   // || short-circuits: no shift-by-64
      if (ok) atomicAdd(&sh.hist[(u32)((k >> d) & 255)], 1u);
    }
    __syncthreads();
    if (tid == 0) {
      u32 cum = 0, kr = s_krem;
      for (int bin = 255; bin >= 0; --bin) {
        u32 h = sh.hist[bin];
        if (cum + h >= kr) { s_prefix = (s_prefix << 8) | (u32)bin; s_krem = kr - cum; break; }
        cum += h;
      }
    }
    __syncthreads();
  }
  const u64 T = s_prefix;   // exact 1000th-largest key (keys are unique)

  // ---- B: compact + bitonic sort (store inverted keys, sort ascending) ----
  sh.skeys[tid] = ~0ULL;
  __syncthreads();
  for (int i = tid; i < NANCH; i += 1024) {
    u64 k = bkeys[i];
    if (k >= T) { u32 p = atomicAdd(&s_cnt, 1u); if (p < 1024) sh.skeys[p] = ~k; }
  }
  __syncthreads();

  for (u32 sz = 2; sz <= 1024; sz <<= 1) {
    for (u32 st = sz >> 1; st > 0; st >>= 1) {
      __syncthreads();
      u32 i = tid, j = i ^ st;
      if (j > i) {
        u64 A = sh.skeys[i], B = sh.skeys[j];
        bool up = ((i & sz) == 0);
        if ((A > B) == up) { sh.skeys[i] = B; sh.skeys[j] = A; }
      }
    }
  }
  __syncthreads();

  // ---- C: extract rank tid, gather, max_coord, offset boxes ---------------
  u64 key = ~sh.skeys[tid];
  float score = __uint_as_float((u32)(key >> 32));
  int   idx   = (int)(~(u32)(key & 0xFFFFFFFFu));
  float4 box  = make_float4(0.f, 0.f, 0.f, 0.f);
  int    cls  = 0;
  if (tid < KTOP) {
    long gi = (long)b * NANCH + idx;
    cls = classes[gi];
    box = boxes[gi];
  } else {
    score = 0.0f;
  }
  int valid = (tid < KTOP) && (score >= 0.05f);

  float m = valid ? fmaxf(fmaxf(box.x, box.y), fmaxf(box.z, box.w)) : 0.0f;
  #pragma unroll
  for (int o = 32; o > 0; o >>= 1) m = fmaxf(m, __shfl_xor(m, o, 64));
  if (lane == 0) s_red[tid >> 6] = m;
  __syncthreads();
  if (tid == 0) {
    float mm = 0.0f;
    #pragma unroll
    for (int i2 = 0; i2 < 16; ++i2) mm = fmaxf(mm, s_red[i2]);
    s_maxc = mm;
  }
  __syncthreads();

  float off = __fmul_rn((float)cls, __fadd_rn(s_maxc, 1.0f));
  float X1 = box.x + off, Y1 = box.y + off, X2 = box.z + off, Y2 = box.w + off;

  int gi = b * 1024 + tid;
  t_score[gi] = score;
  t_cls[gi]   = cls;
  t_box[gi]   = box;
  ox1[gi] = X1; oy1[gi] = Y1; ox2[gi] = X2; oy2[gi] = Y2;
  oarea[gi] = __fmul_rn(__fadd_rn(__fsub_rn(X2, X1), 1.0f),
                        __fadd_rn(__fsub_rn(Y2, Y1), 1.0f));
  u64 vb = __ballot(valid != 0);
  if (lane == 0) validbits[b * 16 + (tid >> 6)] = vb;
}

// ---------------------------------------------------------------------------
// K3: suppression matrix build, machine-wide.  thread = (row, wordcol);
// 64 IoUs/thread.  grid = (63, 16).  Same IoU arithmetic as before.
// ---------------------------------------------------------------------------
__global__ void __launch_bounds__(256) fcos_iou_kernel(
    const float* __restrict__ ox1, const float* __restrict__ oy1,
    const float* __restrict__ ox2, const float* __restrict__ oy2,
    const float* __restrict__ oarea, u64* __restrict__ mat)
{
  __shared__ float sx1[1024], sy1[1024], sx2[1024], sy2[1024], sa[1024];
  const int tid = threadIdx.x;
  const int b   = blockIdx.y;
  const int lane = tid & 63;

  for (int k = tid; k < 1024; k += 256) {
    int gi = b * 1024 + k;
    sx1[k] = ox1[gi]; sy1[k] = oy1[gi];
    sx2[k] = ox2[gi]; sy2[k] = oy2[gi];
    sa[k]  = oarea[gi];
  }
  __syncthreads();

  int w = blockIdx.x * 256 + tid;
  if (w >= KTOP * 16) return;
  int r  = w >> 4;
  int wc = w & 15;

  float rx1 = sx1[r], ry1 = sy1[r], rx2 = sx2[r], ry2 = sy2[r], ra = sa[r];
  u64 bits = 0;
  for (int kk = 0; kk < 64; ++kk) {
    int k2 = (kk + lane) & 63;          // lane swizzle: free 2-way banks
    int j  = wc * 64 + k2;
    if (j < KTOP) {
      float xmn = fmaxf(rx1, sx1[j]);
      float ymn = fmaxf(ry1, sy1[j]);
      float xmx = fminf(rx2, sx2[j]);
      float ymx = fminf(ry2, sy2[j]);
      float dx    = fmaxf(__fsub_rn(xmx, xmn), 0.0f);
      float dy    = fmaxf(__fsub_rn(ymx, ymn), 0.0f);
      float inter = __fmul_rn(dx, dy);
      float den   = __fsub_rn(__fadd_rn(ra, sa[j]), inter);
      float iou   = __fdiv_rn(inter, den);
      if (iou > 0.6f) bits |= (1ULL << k2);
    }
  }
  mat[((long)b * KTOP + r) * 16 + wc] = bits;
}

// ---------------------------------------------------------------------------
// K4: serial greedy scan (wave 0; alive-mask trick: keep[i] = bit i of alive)
// then all 4 waves write outputs.  Decision sequence identical to before.
// ---------------------------------------------------------------------------
__global__ void __launch_bounds__(256) fcos_scan_kernel(
    const u64* __restrict__ mat, const u64* __restrict__ validbits,
    const float* __restrict__ t_score, const int* __restrict__ t_cls,
    const float4* __restrict__ t_box, float* __restrict__ out)
{
  __shared__ u64 s_keep[16];
  const int tid = threadIdx.x;
  const int b   = blockIdx.x;
  const int lane = tid & 63;

  if (tid < 64) {
    u64 alive = (lane < 16) ? validbits[b * 16 + lane] : 0;
    u64 keepw = 0;
    const u64* mb = mat + (long)b * KTOP * 16 + (lane & 15);

    #define LOADROW(i) ((i) < KTOP ? mb[(long)(i) * 16] : 0ULL)
    #define STEP(i, c)                                                  \
      {                                                                 \
        int word = (i) >> 6;                                            \
        u64 aw = __shfl(alive, word, 64);                               \
        if ((aw >> ((i) & 63)) & 1ULL) {                                \
          if (lane < 16) alive &= ~(c);                                 \
          if (lane == word) keepw |= (1ULL << ((i) & 63));              \
        }                                                               \
      }

    u64 a0 = LOADROW(0), a1 = LOADROW(1), a2 = LOADROW(2), a3 = LOADROW(3);
    u64 a4 = LOADROW(4), a5 = LOADROW(5), a6 = LOADROW(6), a7 = LOADROW(7);
    for (int g = 0; g < KTOP; g += 8) {
      u64 n0 = LOADROW(g + 8),  n1 = LOADROW(g + 9);
      u64 n2 = LOADROW(g + 10), n3 = LOADROW(g + 11);
      u64 n4 = LOADROW(g + 12), n5 = LOADROW(g + 13);
      u64 n6 = LOADROW(g + 14), n7 = LOADROW(g + 15);
      STEP(g + 0, a0); STEP(g + 1, a1); STEP(g + 2, a2); STEP(g + 3, a3);
      STEP(g + 4, a4); STEP(g + 5, a5); STEP(g + 6, a6); STEP(g + 7, a7);
      a0 = n0; a1 = n1; a2 = n2; a3 = n3; a4 = n4; a5 = n5; a6 = n6; a7 = n7;
    }
    #undef STEP
    #undef LOADROW

    if (lane < 16) s_keep[lane] = keepw;
  }
  __syncthreads();

  for (int i = tid; i < KTOP; i += 256) {
    int kp = (int)((s_keep[i >> 6] >> (i & 63)) & 1ULL);
    float kf = kp ? 1.0f : 0.0f;
    int gi = b * KTOP + i;
    int ti = b * 1024 + i;
    float sc  = t_score[ti];
    int   cls = t_cls[ti];
    float4 bx = t_box[ti];
    out[gi]         = sc * kf;
    out[16000 + gi] = kp ? (float)cls : 0.0f;
    float4 ob = make_float4(bx.x * kf, bx.y * kf, bx.z * kf, bx.w * kf);
    *reinterpret_cast<float4*>(out + 32000 + (long)gi * 4) = ob;
    out[96000 + gi] = kf;
  }
}

// ---------------------------------------------------------------------------
extern "C" void kernel_launch(void* const* d_in, const int* in_sizes, int n_in,
                              void* d_out, int out_size, void* d_ws, size_t ws_size,
                              hipStream_t stream) {
  const float *cls[5], *cnt[5], *reg[5];
  for (int i = 0; i < 5; ++i) {
    cls[i] = (const float*)d_in[3*i + 0];
    cnt[i] = (const float*)d_in[3*i + 1];
    reg[i] = (const float*)d_in[3*i + 2];
  }
  char* ws = (char*)d_ws;
  // Region A: keys (K1 write, K2 read) -- reused as suppression matrix by K3/K4
  u64*    keys    = (u64*)ws;                    // 16*17064*8 = 2,184,192 B
  u64*    mat     = (u64*)ws;                    // 16*1000*16*8 = 2,048,000 B (aliases keys; K3 runs after K2)
  int*    classes = (int*)(ws + 2184192);        // 1,092,096 B
  float4* boxes   = (float4*)(ws + 3276288);     // 4,368,384 B
  // Region D: top-k results (written by K2)
  float*  t_score = (float*)(ws + 7644672);      // 65,536 B
  int*    t_cls   = (int*)  (ws + 7710208);      // 65,536 B
  float4* t_box   = (float4*)(ws + 7775744);     // 262,144 B
  float*  ox1     = (float*)(ws + 8037888);      // 65,536 B
  float*  oy1     = (float*)(ws + 8103424);
  float*  ox2     = (float*)(ws + 8168960);
  float*  oy2     = (float*)(ws + 8234496);
  float*  oarea   = (float*)(ws + 8300032);
  u64*    vbits   = (u64*)  (ws + 8365568);      // 2,048 B   (end ~8.37 MB)
  float*  out     = (float*)d_out;               // 112,000 floats

  dim3 g1((NANCH + 255) / 256, 16);
  fcos_score_kernel<<<g1, 256, 0, stream>>>(
      cls[0], cnt[0], reg[0], cls[1], cnt[1], reg[1], cls[2], cnt[2], reg[2],
      cls[3], cnt[3], reg[3], cls[4], cnt[4], reg[4], keys, classes, boxes);

  fcos_topk_kernel<<<16, 1024, 0, stream>>>(
      keys, classes, boxes, t_score, t_cls, t_box, ox1, oy1, ox2, oy2, oarea, vbits);

  fcos_iou_kernel<<<dim3(63, 16), 256, 0, stream>>>(ox1, oy1, ox2, oy2, oarea, mat);

  fcos_scan_kernel<<<16, 256, 0, stream>>>(mat, vbits, t_score, t_cls, t_box, out);
}

// Round 5
// 324.730 us; speedup vs baseline: 1.9216x; 1.2044x over previous
//
#include <hip/hip_runtime.h>
#include <hip/hip_bf16.h>
#include <cstdint>

#define NANCH 17064
#define KTOP  1000
#define NCLS  80

typedef unsigned long long u64;
typedef unsigned int u32;

__device__ __forceinline__ float sigmoidf_(float x) {
  return 1.0f / (1.0f + expf(-x));
}

// ---------------------------------------------------------------------------
// K1: per-anchor score / class / box decode.  (UNCHANGED from passing version)
// ---------------------------------------------------------------------------
__global__ void __launch_bounds__(256) fcos_score_kernel(
    const float* __restrict__ cls0, const float* __restrict__ cnt0, const float* __restrict__ reg0,
    const float* __restrict__ cls1, const float* __restrict__ cnt1, const float* __restrict__ reg1,
    const float* __restrict__ cls2, const float* __restrict__ cnt2, const float* __restrict__ reg2,
    const float* __restrict__ cls3, const float* __restrict__ cnt3, const float* __restrict__ reg3,
    const float* __restrict__ cls4, const float* __restrict__ cnt4, const float* __restrict__ reg4,
    u64* __restrict__ keys, int* __restrict__ classes, float4* __restrict__ boxes)
{
  int a = blockIdx.x * blockDim.x + threadIdx.x;
  int b = blockIdx.y;
  if (a >= NANCH) return;

  const float *clsP, *cntP, *regP;
  int hw, wlog, stride, half, local;
  if (a < 12800)      { clsP=cls0; cntP=cnt0; regP=reg0; hw=12800; wlog=7; stride=8;   half=4;  local=a; }
  else if (a < 16000) { clsP=cls1; cntP=cnt1; regP=reg1; hw=3200;  wlog=6; stride=16;  half=8;  local=a-12800; }
  else if (a < 16800) { clsP=cls2; cntP=cnt2; regP=reg2; hw=800;   wlog=5; stride=32;  half=16; local=a-16000; }
  else if (a < 17008) { clsP=cls3; cntP=cnt3; regP=reg3; hw=208;   wlog=4; stride=64;  half=32; local=a-16800; }
  else                { clsP=cls4; cntP=cnt4; regP=reg4; hw=56;    wlog=3; stride=128; half=64; local=a-17008; }

  int y = local >> wlog;
  int x = local & ((1 << wlog) - 1);

  const float* cp = clsP + (long)b * NCLS * hw + local;
  float best = -1.0f; int bestc = 0;
  #pragma unroll 4
  for (int c = 0; c < NCLS; ++c) {
    float v = cp[(long)c * hw];
    float s = sigmoidf_(v);
    if (s > best) { best = s; bestc = c; }
  }

  float cs = sigmoidf_(cntP[(long)b * hw + local]);
  float score = __fsqrt_rn(__fmul_rn(best, cs));

  const float* rp = regP + (long)b * 4 * hw + local;
  float r0 = rp[0], r1 = rp[hw], r2 = rp[2*hw], r3 = rp[3*hw];
  float cx = (float)(x * stride + half);
  float cy = (float)(y * stride + half);

  long gi = (long)b * NANCH + a;
  keys[gi]    = ((u64)__float_as_uint(score) << 32) | (u32)(~(u32)a);
  classes[gi] = bestc + 1;
  boxes[gi]   = make_float4(cx - r0, cy - r1, cx + r2, cy + r3);
}

// ---------------------------------------------------------------------------
// K2: per-batch top-1000.  Radix select with per-wave split histograms and
// wave-parallel suffix-scan bin selection (replaces the tid==0 serial scan
// that was ~100us of LDS latency).  Selection math is integer-exact identical
// to the serial version.  Then bitonic sort + gather + offset boxes.
// ---------------------------------------------------------------------------
struct ShmA {
  u64 skeys[1024];      // 8 KB
  u32 hist[256];        // 1 KB  (merged histogram)
  u32 whist[16][256];   // 16 KB (per-wave histograms)
};

__global__ void __launch_bounds__(1024) fcos_topk_kernel(
    const u64* __restrict__ keys, const int* __restrict__ classes,
    const float4* __restrict__ boxes,
    float* __restrict__ t_score, int* __restrict__ t_cls, float4* __restrict__ t_box,
    float* __restrict__ ox1, float* __restrict__ oy1,
    float* __restrict__ ox2, float* __restrict__ oy2,
    float* __restrict__ oarea, u64* __restrict__ validbits)
{
  __shared__ ShmA sh;
  __shared__ u64 s_prefix;
  __shared__ u32 s_krem, s_cnt;
  __shared__ float s_red[16];
  __shared__ float s_maxc;

  const int tid = threadIdx.x;
  const int b   = blockIdx.x;
  const int lane = tid & 63;
  const u64* bkeys = keys + (long)b * NANCH;

  if (tid == 0) { s_prefix = 0; s_krem = KTOP; s_cnt = 0; }
  __syncthreads();

  // ---- A: radix select the 1000th-largest key -----------------------------
  for (int d = 56; d >= 0; d -= 8) {
    // zero per-wave histograms
    for (int i = tid; i < 16 * 256; i += 1024) ((u32*)sh.whist)[i] = 0;
    __syncthreads();
    u64 pfx = s_prefix;
    u32* myh = sh.whist[tid >> 6];
    for (int i = tid; i < NANCH; i += 1024) {
      u64 k = bkeys[i];
      bool ok = (d == 56) || ((k >> (d + 8)) == pfx);   // || short-circuits: no shift-by-64
      if (ok) atomicAdd(&myh[(u32)((k >> d) & 255)], 1u);
    }
    __syncthreads();
    if (tid < 256) {
      u32 s = 0;
      #pragma unroll
      for (int w = 0; w < 16; ++w) s += sh.whist[w][tid];
      sh.hist[tid] = s;
    }
    __syncthreads();
    // wave-parallel selection: 4 bins/lane, suffix-scan across lanes.
    // Reproduces exactly: scan bin 255->0, cum=count(bins>b),
    // select first b with cum+h[b] >= krem, krem -= cum.
    if (tid < 64) {
      u32 h0 = sh.hist[lane * 4 + 0], h1 = sh.hist[lane * 4 + 1];
      u32 h2 = sh.hist[lane * 4 + 2], h3 = sh.hist[lane * 4 + 3];
      u32 lsum = h0 + h1 + h2 + h3;
      u32 incl = lsum;                       // inclusive suffix: count(bins >= 4*lane)
      #pragma unroll
      for (int off = 1; off < 64; off <<= 1) {
        u32 nv = __shfl_down(incl, off, 64);
        if (lane + off < 64) incl += nv;
      }
      u32 kr = s_krem;
      u64 ball = __ballot(incl >= kr);       // nonzero: count(prefix-matched) >= krem
      int selLane = 63 - __clzll(ball);      // highest lane containing the crossing
      if (lane == selLane) {
        u32 A = incl - lsum;                 // count(bins > 4*lane+3)
        u32 cum3 = A;
        u32 cum2 = A + h3;
        u32 cum1 = cum2 + h2;
        u32 cum0 = cum1 + h1;
        int bin; u32 cum;
        if (cum3 + h3 >= kr)      { bin = lane * 4 + 3; cum = cum3; }
        else if (cum2 + h2 >= kr) { bin = lane * 4 + 2; cum = cum2; }
        else if (cum1 + h1 >= kr) { bin = lane * 4 + 1; cum = cum1; }
        else                      { bin = lane * 4 + 0; cum = cum0; }
        s_prefix = (s_prefix << 8) | (u32)bin;
        s_krem   = kr - cum;
      }
    }
    __syncthreads();
  }
  const u64 T = s_prefix;   // exact 1000th-largest key (keys are unique)

  // ---- B: compact + bitonic sort (store inverted keys, sort ascending) ----
  sh.skeys[tid] = ~0ULL;
  __syncthreads();
  for (int i = tid; i < NANCH; i += 1024) {
    u64 k = bkeys[i];
    if (k >= T) { u32 p = atomicAdd(&s_cnt, 1u); if (p < 1024) sh.skeys[p] = ~k; }
  }
  __syncthreads();

  for (u32 sz = 2; sz <= 1024; sz <<= 1) {
    for (u32 st = sz >> 1; st > 0; st >>= 1) {
      __syncthreads();
      u32 i = tid, j = i ^ st;
      if (j > i) {
        u64 A = sh.skeys[i], B = sh.skeys[j];
        bool up = ((i & sz) == 0);
        if ((A > B) == up) { sh.skeys[i] = B; sh.skeys[j] = A; }
      }
    }
  }
  __syncthreads();

  // ---- C: extract rank tid, gather, max_coord, offset boxes ---------------
  u64 key = ~sh.skeys[tid];
  float score = __uint_as_float((u32)(key >> 32));
  int   idx   = (int)(~(u32)(key & 0xFFFFFFFFu));
  float4 box  = make_float4(0.f, 0.f, 0.f, 0.f);
  int    cls  = 0;
  if (tid < KTOP) {
    long gi = (long)b * NANCH + idx;
    cls = classes[gi];
    box = boxes[gi];
  } else {
    score = 0.0f;
  }
  int valid = (tid < KTOP) && (score >= 0.05f);

  float m = valid ? fmaxf(fmaxf(box.x, box.y), fmaxf(box.z, box.w)) : 0.0f;
  #pragma unroll
  for (int o = 32; o > 0; o >>= 1) m = fmaxf(m, __shfl_xor(m, o, 64));
  if (lane == 0) s_red[tid >> 6] = m;
  __syncthreads();
  if (tid == 0) {
    float mm = 0.0f;
    #pragma unroll
    for (int i2 = 0; i2 < 16; ++i2) mm = fmaxf(mm, s_red[i2]);
    s_maxc = mm;
  }
  __syncthreads();

  float off = __fmul_rn((float)cls, __fadd_rn(s_maxc, 1.0f));
  float X1 = box.x + off, Y1 = box.y + off, X2 = box.z + off, Y2 = box.w + off;

  int gi = b * 1024 + tid;
  t_score[gi] = score;
  t_cls[gi]   = cls;
  t_box[gi]   = box;
  ox1[gi] = X1; oy1[gi] = Y1; ox2[gi] = X2; oy2[gi] = Y2;
  oarea[gi] = __fmul_rn(__fadd_rn(__fsub_rn(X2, X1), 1.0f),
                        __fadd_rn(__fsub_rn(Y2, Y1), 1.0f));
  u64 vb = __ballot(valid != 0);
  if (lane == 0) validbits[b * 16 + (tid >> 6)] = vb;
}

// ---------------------------------------------------------------------------
// K3: suppression matrix build, machine-wide.  (UNCHANGED)
// ---------------------------------------------------------------------------
__global__ void __launch_bounds__(256) fcos_iou_kernel(
    const float* __restrict__ ox1, const float* __restrict__ oy1,
    const float* __restrict__ ox2, const float* __restrict__ oy2,
    const float* __restrict__ oarea, u64* __restrict__ mat)
{
  __shared__ float sx1[1024], sy1[1024], sx2[1024], sy2[1024], sa[1024];
  const int tid = threadIdx.x;
  const int b   = blockIdx.y;
  const int lane = tid & 63;

  for (int k = tid; k < 1024; k += 256) {
    int gi = b * 1024 + k;
    sx1[k] = ox1[gi]; sy1[k] = oy1[gi];
    sx2[k] = ox2[gi]; sy2[k] = oy2[gi];
    sa[k]  = oarea[gi];
  }
  __syncthreads();

  int w = blockIdx.x * 256 + tid;
  if (w >= KTOP * 16) return;
  int r  = w >> 4;
  int wc = w & 15;

  float rx1 = sx1[r], ry1 = sy1[r], rx2 = sx2[r], ry2 = sy2[r], ra = sa[r];
  u64 bits = 0;
  for (int kk = 0; kk < 64; ++kk) {
    int k2 = (kk + lane) & 63;          // lane swizzle: free 2-way banks
    int j  = wc * 64 + k2;
    if (j < KTOP) {
      float xmn = fmaxf(rx1, sx1[j]);
      float ymn = fmaxf(ry1, sy1[j]);
      float xmx = fminf(rx2, sx2[j]);
      float ymx = fminf(ry2, sy2[j]);
      float dx    = fmaxf(__fsub_rn(xmx, xmn), 0.0f);
      float dy    = fmaxf(__fsub_rn(ymx, ymn), 0.0f);
      float inter = __fmul_rn(dx, dy);
      float den   = __fsub_rn(__fadd_rn(ra, sa[j]), inter);
      float iou   = __fdiv_rn(inter, den);
      if (iou > 0.6f) bits |= (1ULL << k2);
    }
  }
  mat[((long)b * KTOP + r) * 16 + wc] = bits;
}

// ---------------------------------------------------------------------------
// K4: serial greedy scan + output write.  (UNCHANGED)
// ---------------------------------------------------------------------------
__global__ void __launch_bounds__(256) fcos_scan_kernel(
    const u64* __restrict__ mat, const u64* __restrict__ validbits,
    const float* __restrict__ t_score, const int* __restrict__ t_cls,
    const float4* __restrict__ t_box, float* __restrict__ out)
{
  __shared__ u64 s_keep[16];
  const int tid = threadIdx.x;
  const int b   = blockIdx.x;
  const int lane = tid & 63;

  if (tid < 64) {
    u64 alive = (lane < 16) ? validbits[b * 16 + lane] : 0;
    u64 keepw = 0;
    const u64* mb = mat + (long)b * KTOP * 16 + (lane & 15);

    #define LOADROW(i) ((i) < KTOP ? mb[(long)(i) * 16] : 0ULL)
    #define STEP(i, c)                                                  \
      {                                                                 \
        int word = (i) >> 6;                                            \
        u64 aw = __shfl(alive, word, 64);                               \
        if ((aw >> ((i) & 63)) & 1ULL) {                                \
          if (lane < 16) alive &= ~(c);                                 \
          if (lane == word) keepw |= (1ULL << ((i) & 63));              \
        }                                                               \
      }

    u64 a0 = LOADROW(0), a1 = LOADROW(1), a2 = LOADROW(2), a3 = LOADROW(3);
    u64 a4 = LOADROW(4), a5 = LOADROW(5), a6 = LOADROW(6), a7 = LOADROW(7);
    for (int g = 0; g < KTOP; g += 8) {
      u64 n0 = LOADROW(g + 8),  n1 = LOADROW(g + 9);
      u64 n2 = LOADROW(g + 10), n3 = LOADROW(g + 11);
      u64 n4 = LOADROW(g + 12), n5 = LOADROW(g + 13);
      u64 n6 = LOADROW(g + 14), n7 = LOADROW(g + 15);
      STEP(g + 0, a0); STEP(g + 1, a1); STEP(g + 2, a2); STEP(g + 3, a3);
      STEP(g + 4, a4); STEP(g + 5, a5); STEP(g + 6, a6); STEP(g + 7, a7);
      a0 = n0; a1 = n1; a2 = n2; a3 = n3; a4 = n4; a5 = n5; a6 = n6; a7 = n7;
    }
    #undef STEP
    #undef LOADROW

    if (lane < 16) s_keep[lane] = keepw;
  }
  __syncthreads();

  for (int i = tid; i < KTOP; i += 256) {
    int kp = (int)((s_keep[i >> 6] >> (i & 63)) & 1ULL);
    float kf = kp ? 1.0f : 0.0f;
    int gi = b * KTOP + i;
    int ti = b * 1024 + i;
    float sc  = t_score[ti];
    int   cls = t_cls[ti];
    float4 bx = t_box[ti];
    out[gi]         = sc * kf;
    out[16000 + gi] = kp ? (float)cls : 0.0f;
    float4 ob = make_float4(bx.x * kf, bx.y * kf, bx.z * kf, bx.w * kf);
    *reinterpret_cast<float4*>(out + 32000 + (long)gi * 4) = ob;
    out[96000 + gi] = kf;
  }
}

// ---------------------------------------------------------------------------
extern "C" void kernel_launch(void* const* d_in, const int* in_sizes, int n_in,
                              void* d_out, int out_size, void* d_ws, size_t ws_size,
                              hipStream_t stream) {
  const float *cls[5], *cnt[5], *reg[5];
  for (int i = 0; i < 5; ++i) {
    cls[i] = (const float*)d_in[3*i + 0];
    cnt[i] = (const float*)d_in[3*i + 1];
    reg[i] = (const float*)d_in[3*i + 2];
  }
  char* ws = (char*)d_ws;
  u64*    keys    = (u64*)ws;                    // 16*17064*8 = 2,184,192 B
  u64*    mat     = (u64*)ws;                    // 2,048,000 B (aliases keys; K3 runs after K2)
  int*    classes = (int*)(ws + 2184192);        // 1,092,096 B
  float4* boxes   = (float4*)(ws + 3276288);     // 4,368,384 B
  float*  t_score = (float*)(ws + 7644672);
  int*    t_cls   = (int*)  (ws + 7710208);
  float4* t_box   = (float4*)(ws + 7775744);
  float*  ox1     = (float*)(ws + 8037888);
  float*  oy1     = (float*)(ws + 8103424);
  float*  ox2     = (float*)(ws + 8168960);
  float*  oy2     = (float*)(ws + 8234496);
  float*  oarea   = (float*)(ws + 8300032);
  u64*    vbits   = (u64*)  (ws + 8365568);
  float*  out     = (float*)d_out;

  dim3 g1((NANCH + 255) / 256, 16);
  fcos_score_kernel<<<g1, 256, 0, stream>>>(
      cls[0], cnt[0], reg[0], cls[1], cnt[1], reg[1], cls[2], cnt[2], reg[2],
      cls[3], cnt[3], reg[3], cls[4], cnt[4], reg[4], keys, classes, boxes);

  fcos_topk_kernel<<<16, 1024, 0, stream>>>(
      keys, classes, boxes, t_score, t_cls, t_box, ox1, oy1, ox2, oy2, oarea, vbits);

  fcos_iou_kernel<<<dim3(63, 16), 256, 0, stream>>>(ox1, oy1, ox2, oy2, oarea, mat);

  fcos_scan_kernel<<<16, 256, 0, stream>>>(mat, vbits, t_score, t_cls, t_box, out);
}

// Round 6
// 280.970 us; speedup vs baseline: 2.2208x; 1.1557x over previous
//
#include <hip/hip_runtime.h>
#include <hip/hip_bf16.h>
#include <cstdint>

#define NANCH 17064
#define KTOP  1000
#define NCLS  80

typedef unsigned long long u64;
typedef unsigned int u32;

__device__ __forceinline__ float sigmoidf_(float x) {
  return 1.0f / (1.0f + expf(-x));
}

// ---------------------------------------------------------------------------
// K1: per-anchor score / class / box decode.  (UNCHANGED)
// ---------------------------------------------------------------------------
__global__ void __launch_bounds__(256) fcos_score_kernel(
    const float* __restrict__ cls0, const float* __restrict__ cnt0, const float* __restrict__ reg0,
    const float* __restrict__ cls1, const float* __restrict__ cnt1, const float* __restrict__ reg1,
    const float* __restrict__ cls2, const float* __restrict__ cnt2, const float* __restrict__ reg2,
    const float* __restrict__ cls3, const float* __restrict__ cnt3, const float* __restrict__ reg3,
    const float* __restrict__ cls4, const float* __restrict__ cnt4, const float* __restrict__ reg4,
    u64* __restrict__ keys, int* __restrict__ classes, float4* __restrict__ boxes)
{
  int a = blockIdx.x * blockDim.x + threadIdx.x;
  int b = blockIdx.y;
  if (a >= NANCH) return;

  const float *clsP, *cntP, *regP;
  int hw, wlog, stride, half, local;
  if (a < 12800)      { clsP=cls0; cntP=cnt0; regP=reg0; hw=12800; wlog=7; stride=8;   half=4;  local=a; }
  else if (a < 16000) { clsP=cls1; cntP=cnt1; regP=reg1; hw=3200;  wlog=6; stride=16;  half=8;  local=a-12800; }
  else if (a < 16800) { clsP=cls2; cntP=cnt2; regP=reg2; hw=800;   wlog=5; stride=32;  half=16; local=a-16000; }
  else if (a < 17008) { clsP=cls3; cntP=cnt3; regP=reg3; hw=208;   wlog=4; stride=64;  half=32; local=a-16800; }
  else                { clsP=cls4; cntP=cnt4; regP=reg4; hw=56;    wlog=3; stride=128; half=64; local=a-17008; }

  int y = local >> wlog;
  int x = local & ((1 << wlog) - 1);

  const float* cp = clsP + (long)b * NCLS * hw + local;
  float best = -1.0f; int bestc = 0;
  #pragma unroll 4
  for (int c = 0; c < NCLS; ++c) {
    float v = cp[(long)c * hw];
    float s = sigmoidf_(v);
    if (s > best) { best = s; bestc = c; }
  }

  float cs = sigmoidf_(cntP[(long)b * hw + local]);
  float score = __fsqrt_rn(__fmul_rn(best, cs));

  const float* rp = regP + (long)b * 4 * hw + local;
  float r0 = rp[0], r1 = rp[hw], r2 = rp[2*hw], r3 = rp[3*hw];
  float cx = (float)(x * stride + half);
  float cy = (float)(y * stride + half);

  long gi = (long)b * NANCH + a;
  keys[gi]    = ((u64)__float_as_uint(score) << 32) | (u32)(~(u32)a);
  classes[gi] = bestc + 1;
  boxes[gi]   = make_float4(cx - r0, cy - r1, cx + r2, cy + r3);
}

// ---------------------------------------------------------------------------
// K2: per-batch top-1000 (radix select, wave-parallel bin scan).  (UNCHANGED)
// ---------------------------------------------------------------------------
struct ShmA {
  u64 skeys[1024];      // 8 KB
  u32 hist[256];        // 1 KB
  u32 whist[16][256];   // 16 KB
};

__global__ void __launch_bounds__(1024) fcos_topk_kernel(
    const u64* __restrict__ keys, const int* __restrict__ classes,
    const float4* __restrict__ boxes,
    float* __restrict__ t_score, int* __restrict__ t_cls, float4* __restrict__ t_box,
    float* __restrict__ ox1, float* __restrict__ oy1,
    float* __restrict__ ox2, float* __restrict__ oy2,
    float* __restrict__ oarea, u64* __restrict__ validbits)
{
  __shared__ ShmA sh;
  __shared__ u64 s_prefix;
  __shared__ u32 s_krem, s_cnt;
  __shared__ float s_red[16];
  __shared__ float s_maxc;

  const int tid = threadIdx.x;
  const int b   = blockIdx.x;
  const int lane = tid & 63;
  const u64* bkeys = keys + (long)b * NANCH;

  if (tid == 0) { s_prefix = 0; s_krem = KTOP; s_cnt = 0; }
  __syncthreads();

  for (int d = 56; d >= 0; d -= 8) {
    for (int i = tid; i < 16 * 256; i += 1024) ((u32*)sh.whist)[i] = 0;
    __syncthreads();
    u64 pfx = s_prefix;
    u32* myh = sh.whist[tid >> 6];
    for (int i = tid; i < NANCH; i += 1024) {
      u64 k = bkeys[i];
      bool ok = (d == 56) || ((k >> (d + 8)) == pfx);
      if (ok) atomicAdd(&myh[(u32)((k >> d) & 255)], 1u);
    }
    __syncthreads();
    if (tid < 256) {
      u32 s = 0;
      #pragma unroll
      for (int w = 0; w < 16; ++w) s += sh.whist[w][tid];
      sh.hist[tid] = s;
    }
    __syncthreads();
    if (tid < 64) {
      u32 h0 = sh.hist[lane * 4 + 0], h1 = sh.hist[lane * 4 + 1];
      u32 h2 = sh.hist[lane * 4 + 2], h3 = sh.hist[lane * 4 + 3];
      u32 lsum = h0 + h1 + h2 + h3;
      u32 incl = lsum;
      #pragma unroll
      for (int off = 1; off < 64; off <<= 1) {
        u32 nv = __shfl_down(incl, off, 64);
        if (lane + off < 64) incl += nv;
      }
      u32 kr = s_krem;
      u64 ball = __ballot(incl >= kr);
      int selLane = 63 - __clzll(ball);
      if (lane == selLane) {
        u32 A = incl - lsum;
        u32 cum3 = A;
        u32 cum2 = A + h3;
        u32 cum1 = cum2 + h2;
        u32 cum0 = cum1 + h1;
        int bin; u32 cum;
        if (cum3 + h3 >= kr)      { bin = lane * 4 + 3; cum = cum3; }
        else if (cum2 + h2 >= kr) { bin = lane * 4 + 2; cum = cum2; }
        else if (cum1 + h1 >= kr) { bin = lane * 4 + 1; cum = cum1; }
        else                      { bin = lane * 4 + 0; cum = cum0; }
        s_prefix = (s_prefix << 8) | (u32)bin;
        s_krem   = kr - cum;
      }
    }
    __syncthreads();
  }
  const u64 T = s_prefix;

  sh.skeys[tid] = ~0ULL;
  __syncthreads();
  for (int i = tid; i < NANCH; i += 1024) {
    u64 k = bkeys[i];
    if (k >= T) { u32 p = atomicAdd(&s_cnt, 1u); if (p < 1024) sh.skeys[p] = ~k; }
  }
  __syncthreads();

  for (u32 sz = 2; sz <= 1024; sz <<= 1) {
    for (u32 st = sz >> 1; st > 0; st >>= 1) {
      __syncthreads();
      u32 i = tid, j = i ^ st;
      if (j > i) {
        u64 A = sh.skeys[i], B = sh.skeys[j];
        bool up = ((i & sz) == 0);
        if ((A > B) == up) { sh.skeys[i] = B; sh.skeys[j] = A; }
      }
    }
  }
  __syncthreads();

  u64 key = ~sh.skeys[tid];
  float score = __uint_as_float((u32)(key >> 32));
  int   idx   = (int)(~(u32)(key & 0xFFFFFFFFu));
  float4 box  = make_float4(0.f, 0.f, 0.f, 0.f);
  int    cls  = 0;
  if (tid < KTOP) {
    long gi = (long)b * NANCH + idx;
    cls = classes[gi];
    box = boxes[gi];
  } else {
    score = 0.0f;
  }
  int valid = (tid < KTOP) && (score >= 0.05f);

  float m = valid ? fmaxf(fmaxf(box.x, box.y), fmaxf(box.z, box.w)) : 0.0f;
  #pragma unroll
  for (int o = 32; o > 0; o >>= 1) m = fmaxf(m, __shfl_xor(m, o, 64));
  if (lane == 0) s_red[tid >> 6] = m;
  __syncthreads();
  if (tid == 0) {
    float mm = 0.0f;
    #pragma unroll
    for (int i2 = 0; i2 < 16; ++i2) mm = fmaxf(mm, s_red[i2]);
    s_maxc = mm;
  }
  __syncthreads();

  float off = __fmul_rn((float)cls, __fadd_rn(s_maxc, 1.0f));
  float X1 = box.x + off, Y1 = box.y + off, X2 = box.z + off, Y2 = box.w + off;

  int gi = b * 1024 + tid;
  t_score[gi] = score;
  t_cls[gi]   = cls;
  t_box[gi]   = box;
  ox1[gi] = X1; oy1[gi] = Y1; ox2[gi] = X2; oy2[gi] = Y2;
  oarea[gi] = __fmul_rn(__fadd_rn(__fsub_rn(X2, X1), 1.0f),
                        __fadd_rn(__fsub_rn(Y2, Y1), 1.0f));
  u64 vb = __ballot(valid != 0);
  if (lane == 0) validbits[b * 16 + (tid >> 6)] = vb;
}

// ---------------------------------------------------------------------------
// K3: suppression matrix build.  (UNCHANGED)
// ---------------------------------------------------------------------------
__global__ void __launch_bounds__(256) fcos_iou_kernel(
    const float* __restrict__ ox1, const float* __restrict__ oy1,
    const float* __restrict__ ox2, const float* __restrict__ oy2,
    const float* __restrict__ oarea, u64* __restrict__ mat)
{
  __shared__ float sx1[1024], sy1[1024], sx2[1024], sy2[1024], sa[1024];
  const int tid = threadIdx.x;
  const int b   = blockIdx.y;
  const int lane = tid & 63;

  for (int k = tid; k < 1024; k += 256) {
    int gi = b * 1024 + k;
    sx1[k] = ox1[gi]; sy1[k] = oy1[gi];
    sx2[k] = ox2[gi]; sy2[k] = oy2[gi];
    sa[k]  = oarea[gi];
  }
  __syncthreads();

  int w = blockIdx.x * 256 + tid;
  if (w >= KTOP * 16) return;
  int r  = w >> 4;
  int wc = w & 15;

  float rx1 = sx1[r], ry1 = sy1[r], rx2 = sx2[r], ry2 = sy2[r], ra = sa[r];
  u64 bits = 0;
  for (int kk = 0; kk < 64; ++kk) {
    int k2 = (kk + lane) & 63;
    int j  = wc * 64 + k2;
    if (j < KTOP) {
      float xmn = fmaxf(rx1, sx1[j]);
      float ymn = fmaxf(ry1, sy1[j]);
      float xmx = fminf(rx2, sx2[j]);
      float ymx = fminf(ry2, sy2[j]);
      float dx    = fmaxf(__fsub_rn(xmx, xmn), 0.0f);
      float dy    = fmaxf(__fsub_rn(ymx, ymn), 0.0f);
      float inter = __fmul_rn(dx, dy);
      float den   = __fsub_rn(__fadd_rn(ra, sa[j]), inter);
      float iou   = __fdiv_rn(inter, den);
      if (iou > 0.6f) bits |= (1ULL << k2);
    }
  }
  mat[((long)b * KTOP + r) * 16 + wc] = bits;
}

// ---------------------------------------------------------------------------
// K4: greedy scan, group-diagonal form.  16 groups of 64 rows.  Phase A:
// unrolled 64-step recurrence on the group's diagonal words via readlane
// (no ds_bpermute in the chain).  Phase B: lanes (q,r) OR keep-masked row
// words (16 pipelined loads) to update the alive mask.  Decision sequence
// is bit-identical to the reference fori_loop.
// ---------------------------------------------------------------------------
__global__ void __launch_bounds__(256) fcos_scan_kernel(
    const u64* __restrict__ mat, const u64* __restrict__ validbits,
    const float* __restrict__ t_score, const int* __restrict__ t_cls,
    const float4* __restrict__ t_box, float* __restrict__ out)
{
  __shared__ u64 s_keep[16];
  const int tid = threadIdx.x;
  const int b   = blockIdx.x;

  if (tid < 64) {
    const int lane = tid;
    const int q = lane >> 4, r = lane & 15;
    const u64* mb = mat + (long)b * KTOP * 16;
    u64 alive = (lane < 16) ? validbits[b * 16 + lane] : 0;

    // diagonal word of group 0 (rows 0..63 all < KTOP)
    u64 dw = mb[(long)lane * 16 + 0];

    for (int g = 0; g < 16; ++g) {
      // prefetch next group's diagonal word (independent of the chain)
      u64 dwn = 0;
      if (g < 15) {
        int rn = (g + 1) * 64 + lane; if (rn > KTOP - 1) rn = KTOP - 1;
        dwn = mb[(long)rn * 16 + (g + 1)];
      }

      // ---- phase A: decide keeps for rows g*64..g*64+63 ------------------
      u64 aw = __shfl(alive, g, 64);   // alive word g (test bits for this group)
      u64 s  = ~aw;                    // suppressed-or-invalid
      u64 keepm = 0;
      #pragma unroll
      for (int i = 0; i < 64; ++i) {
        u64 rowm = __shfl(dw, i, 64);          // const lane -> v_readlane
        u64 kb   = ((~s) >> i) & 1ull;         // keep bit (uniform)
        keepm |= kb << i;
        s     |= rowm & (0ull - kb);           // OR row's in-group mask if kept
      }
      if (lane == 0) s_keep[g] = keepm;

      // ---- phase B: apply kept rows' full masks to alive -----------------
      u64 rem = 0;
      #pragma unroll
      for (int t = 0; t < 16; ++t) {
        int i   = q * 16 + t;
        int row = g * 64 + i; if (row > KTOP - 1) row = KTOP - 1;
        u64 wv  = mb[(long)row * 16 + r];      // 16 independent loads, pipelined
        rem |= wv & (0ull - ((keepm >> i) & 1ull));
      }
      rem |= __shfl_xor(rem, 16, 64);
      rem |= __shfl_xor(rem, 32, 64);
      if (lane < 16) alive &= ~rem;

      dw = dwn;
    }
  }
  __syncthreads();

  for (int i = tid; i < KTOP; i += 256) {
    int kp = (int)((s_keep[i >> 6] >> (i & 63)) & 1ULL);
    float kf = kp ? 1.0f : 0.0f;
    int gi = b * KTOP + i;
    int ti = b * 1024 + i;
    float sc  = t_score[ti];
    int   cls = t_cls[ti];
    float4 bx = t_box[ti];
    out[gi]         = sc * kf;
    out[16000 + gi] = kp ? (float)cls : 0.0f;
    float4 ob = make_float4(bx.x * kf, bx.y * kf, bx.z * kf, bx.w * kf);
    *reinterpret_cast<float4*>(out + 32000 + (long)gi * 4) = ob;
    out[96000 + gi] = kf;
  }
}

// ---------------------------------------------------------------------------
extern "C" void kernel_launch(void* const* d_in, const int* in_sizes, int n_in,
                              void* d_out, int out_size, void* d_ws, size_t ws_size,
                              hipStream_t stream) {
  const float *cls[5], *cnt[5], *reg[5];
  for (int i = 0; i < 5; ++i) {
    cls[i] = (const float*)d_in[3*i + 0];
    cnt[i] = (const float*)d_in[3*i + 1];
    reg[i] = (const float*)d_in[3*i + 2];
  }
  char* ws = (char*)d_ws;
  u64*    keys    = (u64*)ws;                    // 16*17064*8 = 2,184,192 B
  u64*    mat     = (u64*)ws;                    // 2,048,000 B (aliases keys; K3 runs after K2)
  int*    classes = (int*)(ws + 2184192);        // 1,092,096 B
  float4* boxes   = (float4*)(ws + 3276288);     // 4,368,384 B
  float*  t_score = (float*)(ws + 7644672);
  int*    t_cls   = (int*)  (ws + 7710208);
  float4* t_box   = (float4*)(ws + 7775744);
  float*  ox1     = (float*)(ws + 8037888);
  float*  oy1     = (float*)(ws + 8103424);
  float*  ox2     = (float*)(ws + 8168960);
  float*  oy2     = (float*)(ws + 8234496);
  float*  oarea   = (float*)(ws + 8300032);
  u64*    vbits   = (u64*)  (ws + 8365568);
  float*  out     = (float*)d_out;

  dim3 g1((NANCH + 255) / 256, 16);
  fcos_score_kernel<<<g1, 256, 0, stream>>>(
      cls[0], cnt[0], reg[0], cls[1], cnt[1], reg[1], cls[2], cnt[2], reg[2],
      cls[3], cnt[3], reg[3], cls[4], cnt[4], reg[4], keys, classes, boxes);

  fcos_topk_kernel<<<16, 1024, 0, stream>>>(
      keys, classes, boxes, t_score, t_cls, t_box, ox1, oy1, ox2, oy2, oarea, vbits);

  fcos_iou_kernel<<<dim3(63, 16), 256, 0, stream>>>(ox1, oy1, ox2, oy2, oarea, mat);

  fcos_scan_kernel<<<16, 256, 0, stream>>>(mat, vbits, t_score, t_cls, t_box, out);
}

// Round 7
// 256.150 us; speedup vs baseline: 2.4360x; 1.0969x over previous
//
#include <hip/hip_runtime.h>
#include <hip/hip_bf16.h>
#include <cstdint>

#define NANCH 17064
#define KTOP  1000
#define NCLS  80

typedef unsigned long long u64;
typedef unsigned int u32;

__device__ __forceinline__ float sigmoidf_(float x) {
  return 1.0f / (1.0f + expf(-x));
}

// v_readlane-based 64-bit broadcast: no DS pipe, no lgkmcnt, pre-issuable.
__device__ __forceinline__ u64 readlane_u64(u64 v, int l) {
  u32 lo = (u32)__builtin_amdgcn_readlane((int)(u32)v, l);
  u32 hi = (u32)__builtin_amdgcn_readlane((int)(u32)(v >> 32), l);
  return ((u64)hi << 32) | lo;
}

// ---------------------------------------------------------------------------
// K1: per-anchor score / class / box decode.  (UNCHANGED)
// ---------------------------------------------------------------------------
__global__ void __launch_bounds__(256) fcos_score_kernel(
    const float* __restrict__ cls0, const float* __restrict__ cnt0, const float* __restrict__ reg0,
    const float* __restrict__ cls1, const float* __restrict__ cnt1, const float* __restrict__ reg1,
    const float* __restrict__ cls2, const float* __restrict__ cnt2, const float* __restrict__ reg2,
    const float* __restrict__ cls3, const float* __restrict__ cnt3, const float* __restrict__ reg3,
    const float* __restrict__ cls4, const float* __restrict__ cnt4, const float* __restrict__ reg4,
    u64* __restrict__ keys, int* __restrict__ classes, float4* __restrict__ boxes)
{
  int a = blockIdx.x * blockDim.x + threadIdx.x;
  int b = blockIdx.y;
  if (a >= NANCH) return;

  const float *clsP, *cntP, *regP;
  int hw, wlog, stride, half, local;
  if (a < 12800)      { clsP=cls0; cntP=cnt0; regP=reg0; hw=12800; wlog=7; stride=8;   half=4;  local=a; }
  else if (a < 16000) { clsP=cls1; cntP=cnt1; regP=reg1; hw=3200;  wlog=6; stride=16;  half=8;  local=a-12800; }
  else if (a < 16800) { clsP=cls2; cntP=cnt2; regP=reg2; hw=800;   wlog=5; stride=32;  half=16; local=a-16000; }
  else if (a < 17008) { clsP=cls3; cntP=cnt3; regP=reg3; hw=208;   wlog=4; stride=64;  half=32; local=a-16800; }
  else                { clsP=cls4; cntP=cnt4; regP=reg4; hw=56;    wlog=3; stride=128; half=64; local=a-17008; }

  int y = local >> wlog;
  int x = local & ((1 << wlog) - 1);

  const float* cp = clsP + (long)b * NCLS * hw + local;
  float best = -1.0f; int bestc = 0;
  #pragma unroll 4
  for (int c = 0; c < NCLS; ++c) {
    float v = cp[(long)c * hw];
    float s = sigmoidf_(v);
    if (s > best) { best = s; bestc = c; }
  }

  float cs = sigmoidf_(cntP[(long)b * hw + local]);
  float score = __fsqrt_rn(__fmul_rn(best, cs));

  const float* rp = regP + (long)b * 4 * hw + local;
  float r0 = rp[0], r1 = rp[hw], r2 = rp[2*hw], r3 = rp[3*hw];
  float cx = (float)(x * stride + half);
  float cy = (float)(y * stride + half);

  long gi = (long)b * NANCH + a;
  keys[gi]    = ((u64)__float_as_uint(score) << 32) | (u32)(~(u32)a);
  classes[gi] = bestc + 1;
  boxes[gi]   = make_float4(cx - r0, cy - r1, cx + r2, cy + r3);
}

// ---------------------------------------------------------------------------
// K2: per-batch top-1000 (radix select, wave-parallel bin scan).  (UNCHANGED)
// ---------------------------------------------------------------------------
struct ShmA {
  u64 skeys[1024];      // 8 KB
  u32 hist[256];        // 1 KB
  u32 whist[16][256];   // 16 KB
};

__global__ void __launch_bounds__(1024) fcos_topk_kernel(
    const u64* __restrict__ keys, const int* __restrict__ classes,
    const float4* __restrict__ boxes,
    float* __restrict__ t_score, int* __restrict__ t_cls, float4* __restrict__ t_box,
    float* __restrict__ ox1, float* __restrict__ oy1,
    float* __restrict__ ox2, float* __restrict__ oy2,
    float* __restrict__ oarea, u64* __restrict__ validbits)
{
  __shared__ ShmA sh;
  __shared__ u64 s_prefix;
  __shared__ u32 s_krem, s_cnt;
  __shared__ float s_red[16];
  __shared__ float s_maxc;

  const int tid = threadIdx.x;
  const int b   = blockIdx.x;
  const int lane = tid & 63;
  const u64* bkeys = keys + (long)b * NANCH;

  if (tid == 0) { s_prefix = 0; s_krem = KTOP; s_cnt = 0; }
  __syncthreads();

  for (int d = 56; d >= 0; d -= 8) {
    for (int i = tid; i < 16 * 256; i += 1024) ((u32*)sh.whist)[i] = 0;
    __syncthreads();
    u64 pfx = s_prefix;
    u32* myh = sh.whist[tid >> 6];
    for (int i = tid; i < NANCH; i += 1024) {
      u64 k = bkeys[i];
      bool ok = (d == 56) || ((k >> (d + 8)) == pfx);
      if (ok) atomicAdd(&myh[(u32)((k >> d) & 255)], 1u);
    }
    __syncthreads();
    if (tid < 256) {
      u32 s = 0;
      #pragma unroll
      for (int w = 0; w < 16; ++w) s += sh.whist[w][tid];
      sh.hist[tid] = s;
    }
    __syncthreads();
    if (tid < 64) {
      u32 h0 = sh.hist[lane * 4 + 0], h1 = sh.hist[lane * 4 + 1];
      u32 h2 = sh.hist[lane * 4 + 2], h3 = sh.hist[lane * 4 + 3];
      u32 lsum = h0 + h1 + h2 + h3;
      u32 incl = lsum;
      #pragma unroll
      for (int off = 1; off < 64; off <<= 1) {
        u32 nv = __shfl_down(incl, off, 64);
        if (lane + off < 64) incl += nv;
      }
      u32 kr = s_krem;
      u64 ball = __ballot(incl >= kr);
      int selLane = 63 - __clzll(ball);
      if (lane == selLane) {
        u32 A = incl - lsum;
        u32 cum3 = A;
        u32 cum2 = A + h3;
        u32 cum1 = cum2 + h2;
        u32 cum0 = cum1 + h1;
        int bin; u32 cum;
        if (cum3 + h3 >= kr)      { bin = lane * 4 + 3; cum = cum3; }
        else if (cum2 + h2 >= kr) { bin = lane * 4 + 2; cum = cum2; }
        else if (cum1 + h1 >= kr) { bin = lane * 4 + 1; cum = cum1; }
        else                      { bin = lane * 4 + 0; cum = cum0; }
        s_prefix = (s_prefix << 8) | (u32)bin;
        s_krem   = kr - cum;
      }
    }
    __syncthreads();
  }
  const u64 T = s_prefix;

  sh.skeys[tid] = ~0ULL;
  __syncthreads();
  for (int i = tid; i < NANCH; i += 1024) {
    u64 k = bkeys[i];
    if (k >= T) { u32 p = atomicAdd(&s_cnt, 1u); if (p < 1024) sh.skeys[p] = ~k; }
  }
  __syncthreads();

  for (u32 sz = 2; sz <= 1024; sz <<= 1) {
    for (u32 st = sz >> 1; st > 0; st >>= 1) {
      __syncthreads();
      u32 i = tid, j = i ^ st;
      if (j > i) {
        u64 A = sh.skeys[i], B = sh.skeys[j];
        bool up = ((i & sz) == 0);
        if ((A > B) == up) { sh.skeys[i] = B; sh.skeys[j] = A; }
      }
    }
  }
  __syncthreads();

  u64 key = ~sh.skeys[tid];
  float score = __uint_as_float((u32)(key >> 32));
  int   idx   = (int)(~(u32)(key & 0xFFFFFFFFu));
  float4 box  = make_float4(0.f, 0.f, 0.f, 0.f);
  int    cls  = 0;
  if (tid < KTOP) {
    long gi = (long)b * NANCH + idx;
    cls = classes[gi];
    box = boxes[gi];
  } else {
    score = 0.0f;
  }
  int valid = (tid < KTOP) && (score >= 0.05f);

  float m = valid ? fmaxf(fmaxf(box.x, box.y), fmaxf(box.z, box.w)) : 0.0f;
  #pragma unroll
  for (int o = 32; o > 0; o >>= 1) m = fmaxf(m, __shfl_xor(m, o, 64));
  if (lane == 0) s_red[tid >> 6] = m;
  __syncthreads();
  if (tid == 0) {
    float mm = 0.0f;
    #pragma unroll
    for (int i2 = 0; i2 < 16; ++i2) mm = fmaxf(mm, s_red[i2]);
    s_maxc = mm;
  }
  __syncthreads();

  float off = __fmul_rn((float)cls, __fadd_rn(s_maxc, 1.0f));
  float X1 = box.x + off, Y1 = box.y + off, X2 = box.z + off, Y2 = box.w + off;

  int gi = b * 1024 + tid;
  t_score[gi] = score;
  t_cls[gi]   = cls;
  t_box[gi]   = box;
  ox1[gi] = X1; oy1[gi] = Y1; ox2[gi] = X2; oy2[gi] = Y2;
  oarea[gi] = __fmul_rn(__fadd_rn(__fsub_rn(X2, X1), 1.0f),
                        __fadd_rn(__fsub_rn(Y2, Y1), 1.0f));
  u64 vb = __ballot(valid != 0);
  if (lane == 0) validbits[b * 16 + (tid >> 6)] = vb;
}

// ---------------------------------------------------------------------------
// K3: suppression matrix build.  (UNCHANGED)
// ---------------------------------------------------------------------------
__global__ void __launch_bounds__(256) fcos_iou_kernel(
    const float* __restrict__ ox1, const float* __restrict__ oy1,
    const float* __restrict__ ox2, const float* __restrict__ oy2,
    const float* __restrict__ oarea, u64* __restrict__ mat)
{
  __shared__ float sx1[1024], sy1[1024], sx2[1024], sy2[1024], sa[1024];
  const int tid = threadIdx.x;
  const int b   = blockIdx.y;
  const int lane = tid & 63;

  for (int k = tid; k < 1024; k += 256) {
    int gi = b * 1024 + k;
    sx1[k] = ox1[gi]; sy1[k] = oy1[gi];
    sx2[k] = ox2[gi]; sy2[k] = oy2[gi];
    sa[k]  = oarea[gi];
  }
  __syncthreads();

  int w = blockIdx.x * 256 + tid;
  if (w >= KTOP * 16) return;
  int r  = w >> 4;
  int wc = w & 15;

  float rx1 = sx1[r], ry1 = sy1[r], rx2 = sx2[r], ry2 = sy2[r], ra = sa[r];
  u64 bits = 0;
  for (int kk = 0; kk < 64; ++kk) {
    int k2 = (kk + lane) & 63;
    int j  = wc * 64 + k2;
    if (j < KTOP) {
      float xmn = fmaxf(rx1, sx1[j]);
      float ymn = fmaxf(ry1, sy1[j]);
      float xmx = fminf(rx2, sx2[j]);
      float ymx = fminf(ry2, sy2[j]);
      float dx    = fmaxf(__fsub_rn(xmx, xmn), 0.0f);
      float dy    = fmaxf(__fsub_rn(ymx, ymn), 0.0f);
      float inter = __fmul_rn(dx, dy);
      float den   = __fsub_rn(__fadd_rn(ra, sa[j]), inter);
      float iou   = __fdiv_rn(inter, den);
      if (iou > 0.6f) bits |= (1ULL << k2);
    }
  }
  mat[((long)b * KTOP + r) * 16 + wc] = bits;
}

// ---------------------------------------------------------------------------
// K4: greedy scan, group-diagonal form.  Phase A now uses v_readlane
// (register-file broadcast, no DS pipe) so the 64-step recurrence chain is
// pure ALU; the readlanes are chain-independent and pre-issue.  Decision
// sequence is bit-identical to the reference fori_loop.
// ---------------------------------------------------------------------------
__global__ void __launch_bounds__(256) fcos_scan_kernel(
    const u64* __restrict__ mat, const u64* __restrict__ validbits,
    const float* __restrict__ t_score, const int* __restrict__ t_cls,
    const float4* __restrict__ t_box, float* __restrict__ out)
{
  __shared__ u64 s_keep[16];
  const int tid = threadIdx.x;
  const int b   = blockIdx.x;

  if (tid < 64) {
    const int lane = tid;
    const int q = lane >> 4, r = lane & 15;
    const u64* mb = mat + (long)b * KTOP * 16;
    u64 alive = (lane < 16) ? validbits[b * 16 + lane] : 0;

    // diagonal word of group 0 (rows 0..63 all < KTOP)
    u64 dw = mb[(long)lane * 16 + 0];

    for (int g = 0; g < 16; ++g) {
      // prefetch next group's diagonal word (independent of the chain)
      u64 dwn = 0;
      if (g < 15) {
        int rn = (g + 1) * 64 + lane; if (rn > KTOP - 1) rn = KTOP - 1;
        dwn = mb[(long)rn * 16 + (g + 1)];
      }

      // ---- phase A: decide keeps for rows g*64..g*64+63 ------------------
      u64 aw = readlane_u64(alive, g);  // alive word g (test bits, uniform)
      u64 s  = ~aw;                     // suppressed-or-invalid
      u64 keepm = 0;
      #pragma unroll
      for (int i = 0; i < 64; ++i) {
        u64 rowm = readlane_u64(dw, i);        // v_readlane imm: no DS latency
        u64 kb   = ((~s) >> i) & 1ull;         // keep bit (uniform)
        keepm |= kb << i;
        s     |= rowm & (0ull - kb);           // OR row's in-group mask if kept
      }
      if (lane == 0) s_keep[g] = keepm;

      // ---- phase B: apply kept rows' full masks to alive -----------------
      u64 rem = 0;
      #pragma unroll
      for (int t = 0; t < 16; ++t) {
        int i   = q * 16 + t;
        int row = g * 64 + i; if (row > KTOP - 1) row = KTOP - 1;
        u64 wv  = mb[(long)row * 16 + r];      // 16 independent loads, pipelined
        rem |= wv & (0ull - ((keepm >> i) & 1ull));
      }
      rem |= __shfl_xor(rem, 16, 64);
      rem |= __shfl_xor(rem, 32, 64);
      if (lane < 16) alive &= ~rem;

      dw = dwn;
    }
  }
  __syncthreads();

  for (int i = tid; i < KTOP; i += 256) {
    int kp = (int)((s_keep[i >> 6] >> (i & 63)) & 1ULL);
    float kf = kp ? 1.0f : 0.0f;
    int gi = b * KTOP + i;
    int ti = b * 1024 + i;
    float sc  = t_score[ti];
    int   cls = t_cls[ti];
    float4 bx = t_box[ti];
    out[gi]         = sc * kf;
    out[16000 + gi] = kp ? (float)cls : 0.0f;
    float4 ob = make_float4(bx.x * kf, bx.y * kf, bx.z * kf, bx.w * kf);
    *reinterpret_cast<float4*>(out + 32000 + (long)gi * 4) = ob;
    out[96000 + gi] = kf;
  }
}

// ---------------------------------------------------------------------------
extern "C" void kernel_launch(void* const* d_in, const int* in_sizes, int n_in,
                              void* d_out, int out_size, void* d_ws, size_t ws_size,
                              hipStream_t stream) {
  const float *cls[5], *cnt[5], *reg[5];
  for (int i = 0; i < 5; ++i) {
    cls[i] = (const float*)d_in[3*i + 0];
    cnt[i] = (const float*)d_in[3*i + 1];
    reg[i] = (const float*)d_in[3*i + 2];
  }
  char* ws = (char*)d_ws;
  u64*    keys    = (u64*)ws;                    // 16*17064*8 = 2,184,192 B
  u64*    mat     = (u64*)ws;                    // 2,048,000 B (aliases keys; K3 runs after K2)
  int*    classes = (int*)(ws + 2184192);        // 1,092,096 B
  float4* boxes   = (float4*)(ws + 3276288);     // 4,368,384 B
  float*  t_score = (float*)(ws + 7644672);
  int*    t_cls   = (int*)  (ws + 7710208);
  float4* t_box   = (float4*)(ws + 7775744);
  float*  ox1     = (float*)(ws + 8037888);
  float*  oy1     = (float*)(ws + 8103424);
  float*  ox2     = (float*)(ws + 8168960);
  float*  oy2     = (float*)(ws + 8234496);
  float*  oarea   = (float*)(ws + 8300032);
  u64*    vbits   = (u64*)  (ws + 8365568);
  float*  out     = (float*)d_out;

  dim3 g1((NANCH + 255) / 256, 16);
  fcos_score_kernel<<<g1, 256, 0, stream>>>(
      cls[0], cnt[0], reg[0], cls[1], cnt[1], reg[1], cls[2], cnt[2], reg[2],
      cls[3], cnt[3], reg[3], cls[4], cnt[4], reg[4], keys, classes, boxes);

  fcos_topk_kernel<<<16, 1024, 0, stream>>>(
      keys, classes, boxes, t_score, t_cls, t_box, ox1, oy1, ox2, oy2, oarea, vbits);

  fcos_iou_kernel<<<dim3(63, 16), 256, 0, stream>>>(ox1, oy1, ox2, oy2, oarea, mat);

  fcos_scan_kernel<<<16, 256, 0, stream>>>(mat, vbits, t_score, t_cls, t_box, out);
}